// Round 1
// baseline (904.539 us; speedup 1.0000x reference)
//
#include <hip/hip_runtime.h>
#include <cstdio>

typedef unsigned short u16;
typedef float f32x4 __attribute__((ext_vector_type(4)));
typedef __bf16 bf16x8 __attribute__((ext_vector_type(8)));
typedef u16 u16x8 __attribute__((ext_vector_type(8)));
typedef u16 u16x4 __attribute__((ext_vector_type(4)));

__device__ __forceinline__ u16 f2bf(float x) {
  unsigned u = __float_as_uint(x);
  u = (u + 0x7FFFu + ((u >> 16) & 1u)) >> 16;
  return (u16)u;
}

__device__ __forceinline__ f32x4 mfma_bf16(bf16x8 a, bf16x8 b, f32x4 c) {
  return __builtin_amdgcn_mfma_f32_16x16x32_bf16(a, b, c, 0, 0, 0);
}

// C[m,n] = scale * sum_k A[m,k] * B[n,k]   (both operands K-contiguous)
// 128x128 tile, BK=64, 256 threads (4 waves, 2x2 wave grid, 4x4 16x16 frags each)
template <bool BF16OUT, bool SKIP_UPPER, bool KLIMIT>
__global__ __launch_bounds__(256) void gemm_bt(
    const u16* __restrict__ A, const u16* __restrict__ B, void* __restrict__ Cv,
    int K, int lda, int ldb, int ldc,
    long long sAz, long long sBz, long long sCz, float scale)
{
  const int n0 = blockIdx.x * 128;
  const int m0 = blockIdx.y * 128;
  if (SKIP_UPPER && n0 > m0 + 127) return;  // fully-masked score tile (s > t everywhere)
  const int z = blockIdx.z;
  A += (long long)z * sAz;
  B += (long long)z * sBz;

  const int tid = threadIdx.x;
  const int wave = tid >> 6, lane = tid & 63;

  __shared__ u16 lA[128 * 64];
  __shared__ u16 lB[128 * 64];

  f32x4 acc[4][4] = {};

  int kEnd = K;
  if (KLIMIT) { int ke = n0 + 128; kEnd = ke < K ? ke : K; }  // P[t,s]==0 for s>t

  const int srow = wave * 32 + (lane >> 3);
  const int scol = (lane & 7) * 8;
  const u16* gA = A + (long long)(m0 + srow) * lda + scol;
  const u16* gB = B + (long long)(n0 + srow) * ldb + scol;
  const int ldsOff = wave * 2048 + lane * 8;  // == (wave*32 + lane/8)*64 + (lane&7)*8

  const int wm = (wave >> 1) * 64, wn = (wave & 1) * 64;
  const int frow = lane & 15, fk = (lane >> 4) * 8;

  for (int k0 = 0; k0 < kEnd; k0 += 64) {
    u16x8 va[4], vb[4];
#pragma unroll
    for (int i = 0; i < 4; ++i) {
      va[i] = *(const u16x8*)(gA + (long long)i * 8 * lda + k0);
      vb[i] = *(const u16x8*)(gB + (long long)i * 8 * ldb + k0);
    }
    __syncthreads();  // previous compute done before overwriting LDS
#pragma unroll
    for (int i = 0; i < 4; ++i) {
      *(u16x8*)(&lA[ldsOff + i * 512]) = va[i];
      *(u16x8*)(&lB[ldsOff + i * 512]) = vb[i];
    }
    __syncthreads();  // tile visible to all waves
#pragma unroll
    for (int kk = 0; kk < 64; kk += 32) {
      bf16x8 af[4], bfr[4];
#pragma unroll
      for (int m = 0; m < 4; ++m)
        af[m] = *(const bf16x8*)(&lA[(wm + m * 16 + frow) * 64 + kk + fk]);
#pragma unroll
      for (int n = 0; n < 4; ++n)
        bfr[n] = *(const bf16x8*)(&lB[(wn + n * 16 + frow) * 64 + kk + fk]);
#pragma unroll
      for (int m = 0; m < 4; ++m)
#pragma unroll
        for (int n = 0; n < 4; ++n)
          acc[m][n] = mfma_bf16(af[m], bfr[n], acc[m][n]);
    }
  }

  // C/D layout: col = lane&15, row = (lane>>4)*4 + r  [m89-verified]
  const int crow0 = m0 + wm + (lane >> 4) * 4;
  const int ccol0 = n0 + wn + (lane & 15);
  if (BF16OUT) {
    u16* C = (u16*)Cv + (long long)z * sCz;
#pragma unroll
    for (int m = 0; m < 4; ++m)
#pragma unroll
      for (int n = 0; n < 4; ++n)
#pragma unroll
        for (int r = 0; r < 4; ++r)
          C[(long long)(crow0 + m * 16 + r) * ldc + ccol0 + n * 16] = f2bf(acc[m][n][r] * scale);
  } else {
    float* C = (float*)Cv + (long long)z * sCz;
#pragma unroll
    for (int m = 0; m < 4; ++m)
#pragma unroll
      for (int n = 0; n < 4; ++n)
#pragma unroll
        for (int r = 0; r < 4; ++r)
          C[(long long)(crow0 + m * 16 + r) * ldc + ccol0 + n * 16] = acc[m][n][r] * scale;
  }
}

// (b, i, s) fp32  ->  (b, s, i) bf16 ; one 64x64 tile per block, block (64,4)
__global__ __launch_bounds__(256) void conv_transpose(const float* __restrict__ src, u16* __restrict__ dst)
{
  const int b = blockIdx.z;
  const float* s = src + (long long)b * 1024 * 2048;
  u16* d = dst + (long long)b * 2048 * 1024;
  const int s0 = blockIdx.x * 64, i0 = blockIdx.y * 64;
  const int tx = threadIdx.x, ty = threadIdx.y;
  __shared__ float tile[64][65];
#pragma unroll
  for (int r = 0; r < 16; ++r)
    tile[r * 4 + ty][tx] = s[(long long)(i0 + r * 4 + ty) * 2048 + s0 + tx];
  __syncthreads();
#pragma unroll
  for (int r = 0; r < 16; ++r)
    d[(long long)(s0 + r * 4 + ty) * 1024 + i0 + tx] = f2bf(tile[tx][r * 4 + ty]);
}

__global__ __launch_bounds__(256) void conv_weights(
    const float* __restrict__ a, const float* __restrict__ b, const float* __restrict__ c,
    u16* __restrict__ oa, u16* __restrict__ ob, u16* __restrict__ oc)
{
  const int which = blockIdx.y;
  const float* s = which == 0 ? a : which == 1 ? b : c;
  u16* d = which == 0 ? oa : which == 1 ? ob : oc;
  const int idx = (blockIdx.x * 256 + threadIdx.x) * 4;
  f32x4 v = *(const f32x4*)(s + idx);
  u16x4 o;
#pragma unroll
  for (int j = 0; j < 4; ++j) o[j] = f2bf(v[j]);
  *(u16x4*)(d + idx) = o;
}

// Row t of S'[t,s]: mask by index (s<=t), max, sum-exp, write P bf16. One row per block.
__global__ __launch_bounds__(256) void col_softmax(const float* __restrict__ S, u16* __restrict__ P)
{
  const int t = blockIdx.x;
  const long long rowOff = ((long long)blockIdx.y * 2048 + t) * 2048;
  const float* row = S + rowOff;
  u16* prow = P + rowOff;
  const int tid = threadIdx.x;
  const int i0 = tid * 4, i1 = 1024 + tid * 4;

  f32x4 a = *(const f32x4*)(row + i0);
  f32x4 b = *(const f32x4*)(row + i1);
  float v[8];
#pragma unroll
  for (int j = 0; j < 4; ++j) {
    v[j]     = (i0 + j <= t) ? a[j] : -1e30f;  // masked/unwritten entries discarded by index
    v[4 + j] = (i1 + j <= t) ? b[j] : -1e30f;
  }
  float m = v[0];
#pragma unroll
  for (int j = 1; j < 8; ++j) m = fmaxf(m, v[j]);
#pragma unroll
  for (int off = 32; off; off >>= 1) m = fmaxf(m, __shfl_xor(m, off));
  __shared__ float red[4];
  __shared__ float red2[4];
  if ((tid & 63) == 0) red[tid >> 6] = m;
  __syncthreads();
  m = fmaxf(fmaxf(red[0], red[1]), fmaxf(red[2], red[3]));

  float e[8]; float ssum = 0.f;
#pragma unroll
  for (int j = 0; j < 8; ++j) { e[j] = __expf(v[j] - m); ssum += e[j]; }
#pragma unroll
  for (int off = 32; off; off >>= 1) ssum += __shfl_xor(ssum, off);
  if ((tid & 63) == 0) red2[tid >> 6] = ssum;
  __syncthreads();
  ssum = red2[0] + red2[1] + red2[2] + red2[3];
  const float inv = 1.0f / ssum;
  u16x4 o0, o1;
#pragma unroll
  for (int j = 0; j < 4; ++j) { o0[j] = f2bf(e[j] * inv); o1[j] = f2bf(e[4 + j] * inv); }
  *(u16x4*)(prow + i0) = o0;
  *(u16x4*)(prow + i1) = o1;
}

extern "C" void kernel_launch(void* const* d_in, const int* in_sizes, int n_in,
                              void* d_out, int out_size, void* d_ws, size_t ws_size,
                              hipStream_t stream)
{
  const float* Q  = (const float*)d_in[0];
  const float* K  = (const float*)d_in[1];
  const float* V  = (const float*)d_in[2];
  const float* WQ = (const float*)d_in[3];
  const float* WK = (const float*)d_in[4];
  const float* WV = (const float*)d_in[5];
  float* out = (float*)d_out;

  const size_t MB = 1ull << 20;
  char* w = (char*)d_ws;
  if (ws_size < 262 * MB) {
    fprintf(stderr, "kernel_launch: workspace too small (%zu B, need >= %zu B)\n",
            ws_size, (size_t)(262 * MB));
    return;
  }

  // ws layout (MB): [0,6) weights bf16 | [6,70) Qd_t | [70,134) Kd_t | [134,198) Vd
  // [198, ...) transient: transposed-input buffer (64MB), later S(fp32)+P(bf16) chunks
  u16* wq    = (u16*)(w + 0 * MB);
  u16* wk    = (u16*)(w + 2 * MB);
  u16* wv    = (u16*)(w + 4 * MB);
  u16* qdt   = (u16*)(w + 6 * MB);
  u16* kdt   = (u16*)(w + 70 * MB);
  u16* vd    = (u16*)(w + 134 * MB);
  u16* trans = (u16*)(w + 198 * MB);
  float* S   = (float*)(w + 198 * MB);

  long long freeMB = (long long)(ws_size / MB) - 198;
  int chunk = (int)(freeMB / 24);  // 16MB S + 8MB P per batch
  if (chunk > 8) chunk = 8;
  u16* P = (u16*)(w + (198 + (size_t)chunk * 16) * MB);

  conv_weights<<<dim3(1024, 3), 256, 0, stream>>>(WQ, WK, WV, wq, wk, wv);

  // Projections. Qd_t/Kd_t stored (b, seq, o); Vd stored (b, o, seq).
  conv_transpose<<<dim3(32, 16, 16), dim3(64, 4), 0, stream>>>(Q, trans);
  gemm_bt<true, false, false><<<dim3(8, 256, 1), 256, 0, stream>>>(
      trans, wq, qdt, 1024, 1024, 1024, 1024, 0, 0, 0, 1.0f);
  conv_transpose<<<dim3(32, 16, 16), dim3(64, 4), 0, stream>>>(K, trans);
  gemm_bt<true, false, false><<<dim3(8, 256, 1), 256, 0, stream>>>(
      trans, wk, kdt, 1024, 1024, 1024, 1024, 0, 0, 0, 1.0f);
  conv_transpose<<<dim3(32, 16, 16), dim3(64, 4), 0, stream>>>(V, trans);
  gemm_bt<true, false, false><<<dim3(16, 8, 16), 256, 0, stream>>>(
      wv, trans, vd, 1024, 1024, 1024, 2048,
      0, (long long)2048 * 1024, (long long)1024 * 2048, 1.0f);

  // Attention per batch-chunk: S'[t,s] = Kd_t[t,:]·Qd_t[s,:]/32 (skip s>t tiles),
  // row-softmax over s (masked by index), out[o,t] = sum_s Vd[o,s] P[t,s].
  for (int b0 = 0; b0 < 16; b0 += chunk) {
    const int nb = (16 - b0) < chunk ? (16 - b0) : chunk;
    gemm_bt<false, true, false><<<dim3(16, 16, nb), 256, 0, stream>>>(
        kdt + (long long)b0 * 2048 * 1024, qdt + (long long)b0 * 2048 * 1024, S,
        1024, 1024, 1024, 2048,
        (long long)2048 * 1024, (long long)2048 * 1024, (long long)2048 * 2048, 0.03125f);
    col_softmax<<<dim3(2048, nb), 256, 0, stream>>>(S, P);
    gemm_bt<false, false, true><<<dim3(16, 8, nb), 256, 0, stream>>>(
        vd + (long long)b0 * 1024 * 2048, P, out + (long long)b0 * 1024 * 2048,
        2048, 2048, 2048, 2048,
        (long long)1024 * 2048, (long long)2048 * 2048, (long long)1024 * 2048, 1.0f);
  }
}